// Round 6
// baseline (130.125 us; speedup 1.0000x reference)
//
#include <hip/hip_runtime.h>

// RecursiveNN: 11-level binary tree, shared linear map W(128x256)+b, bf16 MFMA.
// Evidence ledger: r4 occupancy 3->4 blocks/CU neutral; r3 L3-warm replay same
// dur; r5 gather-under-compute neutral (phases ~400cyc can't hide ~900cyc mem
// latency). Model: dur ~= phase_count x per-phase latency (issue + dep-chains
// + barrier skew). This round: attack phase count + per-phase ILP + deep-level
// MFMA waste.
//   tree128: one block = 2 groups x 128 leaves (2048 blocks). Each group runs
//   L1h1/L1h2/L2 into a shared 64-row buffer D; deep levels (L3..final) run
//   JOINTLY across both groups: 64->32->16->8->4 roots. Barriers 17->13,
//   MFMA/wave 320->272, deep phases full-width. step32 interleaves both
//   mt-tiles (4 indep MFMA chains, halves dep-chain span per phase).
//   tree32: unchanged (one block = one batch, 32 roots -> 1).
// Numerics: per-acc K-order kh->j = kk0..7 identical to verified r0 kernel.
// LDS: 3 x 64-row STRIDE=136 buffers = 52224 B -> 3 blocks/CU; 0 conflicts
// measured. launch_bounds(256,3): 170-reg budget; est peak ~160. Spill
// tripwire: WRITE_SIZE >> 2 MB.

typedef __bf16 bf16x8 __attribute__((ext_vector_type(8)));
typedef __bf16 bf16x4 __attribute__((ext_vector_type(4)));
typedef float f32x4 __attribute__((ext_vector_type(4)));

#define STRIDE 136  // 128 cols + 8 pad bf16 = 272B rows; 0 LDS conflicts measured

// Pack W (fp32 128x256) into MFMA B-fragment lane order (bf16):
//   frag f=nl*8+kk, wave wv, lane l: elem j = W[o][d+j],
//   o=(2wv+nl)*16+(l&15), d=kk*32+(l>>4)*8; stored at wpack[(f*256+tid)*8].
__global__ void pack_w_kernel(const float* __restrict__ W,
                              __bf16* __restrict__ wpack) {
    const int f = blockIdx.x;
    const int tid = threadIdx.x;
    const int wv = tid >> 6, l = tid & 63;
    const int nl = f >> 3, kk = f & 7;
    const int o = ((wv << 1) + nl) * 16 + (l & 15);
    const int d = kk * 32 + ((l >> 4) << 3);
    const float* src = W + o * 256 + d;
    bf16x8 h;
#pragma unroll
    for (int j = 0; j < 8; ++j) h[j] = (__bf16)src[j];
    *(bf16x8*)(wpack + (size_t)(f * 256 + tid) * 8) = h;
}

// Full-width level step: 64 input rows (src0=0..31, src1=32..63) -> 32 outputs.
// Both mt-tiles interleaved: 4 independent MFMA chains (acc[mt][nl]) so the
// dependent-MFMA span per phase is 8 deep, not 16. Ends in barrier.
__device__ __forceinline__ void step32(
    const __bf16* src0, const __bf16* src1, __bf16* dst,
    const bf16x8* wf, const float* bval, int wv, int q, int lm)
{
    f32x4 acc[2][2];  // [mt][nl]
#pragma unroll
    for (int mt = 0; mt < 2; ++mt)
#pragma unroll
        for (int nl = 0; nl < 2; ++nl)
            acc[mt][nl] = f32x4{ bval[nl], bval[nl], bval[nl], bval[nl] };
#pragma unroll
    for (int kh = 0; kh < 2; ++kh) {            // K half: rows 2lm / 2lm+1
        const int row = 2 * lm + kh;
        bf16x8 a0[4], a1[4];
#pragma unroll
        for (int j = 0; j < 4; ++j) {
            a0[j] = *(const bf16x8*)&src0[row * STRIDE + j * 32 + q * 8];
            a1[j] = *(const bf16x8*)&src1[row * STRIDE + j * 32 + q * 8];
        }
#pragma unroll
        for (int j = 0; j < 4; ++j) {           // kk = kh*4+j: order 0..7 per acc
            acc[0][0] = __builtin_amdgcn_mfma_f32_16x16x32_bf16(
                a0[j], wf[0 * 8 + kh * 4 + j], acc[0][0], 0, 0, 0);
            acc[1][0] = __builtin_amdgcn_mfma_f32_16x16x32_bf16(
                a1[j], wf[0 * 8 + kh * 4 + j], acc[1][0], 0, 0, 0);
            acc[0][1] = __builtin_amdgcn_mfma_f32_16x16x32_bf16(
                a0[j], wf[1 * 8 + kh * 4 + j], acc[0][1], 0, 0, 0);
            acc[1][1] = __builtin_amdgcn_mfma_f32_16x16x32_bf16(
                a1[j], wf[1 * 8 + kh * 4 + j], acc[1][1], 0, 0, 0);
        }
    }
#pragma unroll
    for (int mt = 0; mt < 2; ++mt)
#pragma unroll
        for (int nl = 0; nl < 2; ++nl) {
            const int col = (2 * wv + nl) * 16 + lm;
            const bf16x4 hv = __builtin_convertvector(acc[mt][nl], bf16x4);
#pragma unroll
            for (int r = 0; r < 4; ++r)
                dst[(mt * 16 + q * 4 + r) * STRIDE + col] = hv[r];
        }
    __syncthreads();
}

// Small level step: NOUT (<=16) outputs from 2*NOUT input rows. Ends in barrier.
template <int NOUT>
__device__ __forceinline__ void step_small(
    const __bf16* src, __bf16* dst,
    const bf16x8* wf, const float* bval, int wv, int q, int lm)
{
    const int me = (NOUT >= 16) ? lm : (lm < NOUT ? lm : 0);
    f32x4 acc[2];
    acc[0] = f32x4{ bval[0], bval[0], bval[0], bval[0] };
    acc[1] = f32x4{ bval[1], bval[1], bval[1], bval[1] };
#pragma unroll
    for (int kh = 0; kh < 2; ++kh) {
        const int row = 2 * me + kh;
        bf16x8 af[4];
#pragma unroll
        for (int j = 0; j < 4; ++j)
            af[j] = *(const bf16x8*)&src[row * STRIDE + j * 32 + q * 8];
#pragma unroll
        for (int nl = 0; nl < 2; ++nl)
#pragma unroll
            for (int j = 0; j < 4; ++j)
                acc[nl] = __builtin_amdgcn_mfma_f32_16x16x32_bf16(
                    af[j], wf[nl * 8 + kh * 4 + j], acc[nl], 0, 0, 0);
    }
#pragma unroll
    for (int nl = 0; nl < 2; ++nl) {
        const int col = (2 * wv + nl) * 16 + lm;
        const bf16x4 hv = __builtin_convertvector(acc[nl], bf16x4);
#pragma unroll
        for (int r = 0; r < 4; ++r) {
            const int row = q * 4 + r;
            if (row < NOUT)
                dst[row * STRIDE + col] = hv[r];
        }
    }
    __syncthreads();
}

// Joint final: 8 input rows -> 4 roots (rows 0,1 = group A; 2,3 = group B)
// straight to global (bf16). No barrier.
__device__ __forceinline__ void final4(
    const __bf16* src, __bf16* yrow,
    const bf16x8* wf, const float* bval, int wv, int q, int lm)
{
    const int me = (lm < 4) ? lm : 0;
    f32x4 acc[2];
    acc[0] = f32x4{ bval[0], bval[0], bval[0], bval[0] };
    acc[1] = f32x4{ bval[1], bval[1], bval[1], bval[1] };
#pragma unroll
    for (int kh = 0; kh < 2; ++kh) {
        const int row = 2 * me + kh;
        bf16x8 af[4];
#pragma unroll
        for (int j = 0; j < 4; ++j)
            af[j] = *(const bf16x8*)&src[row * STRIDE + j * 32 + q * 8];
#pragma unroll
        for (int nl = 0; nl < 2; ++nl)
#pragma unroll
            for (int j = 0; j < 4; ++j)
                acc[nl] = __builtin_amdgcn_mfma_f32_16x16x32_bf16(
                    af[j], wf[nl * 8 + kh * 4 + j], acc[nl], 0, 0, 0);
    }
#pragma unroll
    for (int nl = 0; nl < 2; ++nl) {
        const int col = (2 * wv + nl) * 16 + lm;
        if (q == 0) {                 // rows 0..3 = quad 0 regs 0..3
#pragma unroll
            for (int r = 0; r < 4; ++r)
                yrow[r * 128 + col] = (__bf16)acc[nl][r];
        }
    }
}

// Issue 64-row gather (ids wb64[0..63]) into 32 staging VGPRs.
__device__ __forceinline__ void gather_issue(
    const int* wb64, const float* emb, int tid, f32x4 (&s)[8])
{
#pragma unroll
    for (int i = 0; i < 8; ++i) {
        const int id = wb64[(tid >> 5) + 8 * i];
        s[i] = *(const f32x4*)(emb + (size_t)id * 128 + (tid & 31) * 4);
    }
}

// Convert staged fp32 rows -> bf16 LDS rows 0..63 (coalesced 512B per row-group).
__device__ __forceinline__ void gather_write(
    __bf16* dst, int tid, const f32x4 (&s)[8])
{
#pragma unroll
    for (int i = 0; i < 8; ++i) {
        const int row = (tid >> 5) + 8 * i;
        *(bf16x4*)&dst[row * STRIDE + (tid & 31) * 4] =
            __builtin_convertvector(s[i], bf16x4);
    }
}

// Kernel 1: one block = 2 groups x 128 leaves. Phases (13 vs r5's 17):
//  P0: gather gA.h1 -> A                     [exposed prologue]
//  P1: issue gA.h2 | L1h1(gA): A -> B[0:32]
//  P2: write gA.h2 -> A; barrier
//  P3: issue gB.h1 | L1h2(gA): A -> B[32:64]
//  P4: write gB.h1 -> A | L2(gA): B -> D[0:32]
//  P5: issue gB.h2 | L1h1(gB): A -> B[0:32]
//  P6: write gB.h2 -> A; barrier
//  P7: L1h2(gB): A -> B[32:64]
//  P8: L2(gB): B -> D[32:64]
//  P9: joint L3: D[0:64] -> B[0:32]          (full-width, zero waste)
//  P10: joint L4: B[0:32] -> D[0:16]
//  P11: joint L5: D[0:16] -> B[0:8]
//  P12: joint final: B[0:8] -> 4 global root rows (gA:0,1 gB:2,3)
// Joint rows stay group-contiguous at every level (group row-counts even).
__global__ __launch_bounds__(256, 3) void tree128_kernel(
    const int* __restrict__ wid, const float* __restrict__ emb,
    const __bf16* __restrict__ wpack, const float* __restrict__ bias,
    __bf16* __restrict__ yout)
{
    __shared__ __align__(16) __bf16 bufA[64 * STRIDE];  // 17408 B
    __shared__ __align__(16) __bf16 bufB[64 * STRIDE];  // 17408 B
    __shared__ __align__(16) __bf16 bufD[64 * STRIDE];  // 17408 B -> 52224 total
    const int tid = threadIdx.x;
    const int batch = blockIdx.x >> 3;   // 8 pairs (256 leaves each) per batch
    const int pair = blockIdx.x & 7;
    const int wv = tid >> 6, ln = tid & 63, q = ln >> 4, lm = ln & 15;

    // W fragments: 16 x (8 bf16) = 64 regs (AGPR-resident), coalesced 256B/thread.
    bf16x8 wf[16];
    const bf16x8* wp = (const bf16x8*)wpack;
#pragma unroll
    for (int f = 0; f < 16; ++f) wf[f] = wp[f * 256 + tid];
    float bval[2];
    bval[0] = bias[(2 * wv + 0) * 16 + lm];
    bval[1] = bias[(2 * wv + 1) * 16 + lm];

    const int* wb = wid + batch * 2048 + pair * 256;  // 256 leaves for this block
    f32x4 st[8];                                      // 32 staging VGPRs (reused)

    // P0: prologue (only exposed gather).
    gather_issue(wb, emb, tid, st);
    gather_write(bufA, tid, st);
    __syncthreads();
    // P1
    gather_issue(wb + 64, emb, tid, st);
    step32(bufA, bufA + 32 * STRIDE, bufB, wf, bval, wv, q, lm);
    // P2
    gather_write(bufA, tid, st);
    __syncthreads();
    // P3
    gather_issue(wb + 128, emb, tid, st);
    step32(bufA, bufA + 32 * STRIDE, bufB + 32 * STRIDE, wf, bval, wv, q, lm);
    // P4: write gB.h1 under L2(gA); both covered by step32's end barrier.
    gather_write(bufA, tid, st);
    step32(bufB, bufB + 32 * STRIDE, bufD, wf, bval, wv, q, lm);
    // P5
    gather_issue(wb + 192, emb, tid, st);
    step32(bufA, bufA + 32 * STRIDE, bufB, wf, bval, wv, q, lm);
    // P6
    gather_write(bufA, tid, st);
    __syncthreads();
    // P7
    step32(bufA, bufA + 32 * STRIDE, bufB + 32 * STRIDE, wf, bval, wv, q, lm);
    // P8
    step32(bufB, bufB + 32 * STRIDE, bufD + 32 * STRIDE, wf, bval, wv, q, lm);
    // P9: joint L3 (gA rows 0..31, gB rows 32..63)
    step32(bufD, bufD + 32 * STRIDE, bufB, wf, bval, wv, q, lm);
    // P10: joint L4
    step_small<16>(bufB, bufD, wf, bval, wv, q, lm);
    // P11: joint L5
    step_small<8>(bufD, bufB, wf, bval, wv, q, lm);
    // P12: joint final -> 4 root rows
    final4(bufB, yout + (size_t)(batch * 32 + pair * 4) * 128,
           wf, bval, wv, q, lm);
}

// Kernel 2: one block = one batch; 32 subtree roots -> 5 levels -> fp32 row.
__global__ __launch_bounds__(256) void tree32_kernel(
    const __bf16* __restrict__ yin, const __bf16* __restrict__ wpack,
    const float* __restrict__ bias, float* __restrict__ out)
{
    __shared__ __align__(16) __bf16 buf0[32 * STRIDE];  // 8704 B
    __shared__ __align__(16) __bf16 buf1[16 * STRIDE];  // 4352 B
    const int tid = threadIdx.x;
    const int batch = blockIdx.x;
    const int wv = tid >> 6, ln = tid & 63, q = ln >> 4, lm = ln & 15;

    bf16x8 wf[16];
    const bf16x8* wp = (const bf16x8*)wpack;
#pragma unroll
    for (int f = 0; f < 16; ++f) wf[f] = wp[f * 256 + tid];
    float bval[2];
    bval[0] = bias[(2 * wv + 0) * 16 + lm];
    bval[1] = bias[(2 * wv + 1) * 16 + lm];

#pragma unroll
    for (int i = 0; i < 2; ++i) {
        const int flat = tid + 256 * i;
        const int row = flat >> 4;
        const int c8 = flat & 15;
        const bf16x8 v =
            *(const bf16x8*)(yin + (size_t)(batch * 32 + row) * 128 + c8 * 8);
        *(bf16x8*)&buf0[row * STRIDE + c8 * 8] = v;
    }
    __syncthreads();

    step_small<16>(buf0, buf1, wf, bval, wv, q, lm);  // 32->16
    step_small<8> (buf1, buf0, wf, bval, wv, q, lm);  // 16->8
    step_small<4> (buf0, buf1, wf, bval, wv, q, lm);  // 8->4
    step_small<2> (buf1, buf0, wf, bval, wv, q, lm);  // 4->2

    // Final: rows 0,1 of buf0 -> root row (fp32 out).
    {
        f32x4 acc[2];
        acc[0] = f32x4{ bval[0], bval[0], bval[0], bval[0] };
        acc[1] = f32x4{ bval[1], bval[1], bval[1], bval[1] };
#pragma unroll
        for (int kh = 0; kh < 2; ++kh) {
            bf16x8 af[4];
#pragma unroll
            for (int j = 0; j < 4; ++j)
                af[j] = *(const bf16x8*)&buf0[kh * STRIDE + j * 32 + q * 8];
#pragma unroll
            for (int nl = 0; nl < 2; ++nl)
#pragma unroll
                for (int j = 0; j < 4; ++j)
                    acc[nl] = __builtin_amdgcn_mfma_f32_16x16x32_bf16(
                        af[j], wf[nl * 8 + kh * 4 + j], acc[nl], 0, 0, 0);
        }
#pragma unroll
        for (int nl = 0; nl < 2; ++nl) {
            const int col = (2 * wv + nl) * 16 + lm;
            if (q == 0) out[(size_t)batch * 128 + col] = acc[nl][0];
        }
    }
}

extern "C" void kernel_launch(void* const* d_in, const int* in_sizes, int n_in,
                              void* d_out, int out_size, void* d_ws, size_t ws_size,
                              hipStream_t stream) {
    const int*   wid = (const int*)d_in[0];      // (256, 2048) int32
    const float* emb = (const float*)d_in[1];    // (100000, 128) fp32
    const float* W   = (const float*)d_in[2];    // (128, 256) fp32
    const float* b   = (const float*)d_in[3];    // (128,) fp32
    float* out = (float*)d_out;                  // (256, 128) fp32

    __bf16* wpack = (__bf16*)d_ws;               // 32768 elems = 64 KB
    __bf16* y     = wpack + 32768;               // (256,32,128) bf16 = 2 MB

    pack_w_kernel<<<16, 256, 0, stream>>>(W, wpack);
    tree128_kernel<<<2048, 256, 0, stream>>>(wid, emb, wpack, b, y);
    tree32_kernel<<<256, 256, 0, stream>>>(y, wpack, b, out);
}